// Round 15
// baseline (319.049 us; speedup 1.0000x reference)
//
#include <hip/hip_runtime.h>

#define NODES 25088
#define NB 8
#define NPB 3136   // nodes per batch (56*56)
#define C 96
#define KNN 9
#define COUT 192
#define MSPLIT 4   // m-range quarters for knn filter
#define T12 12     // rescore depth per quarter (output)
#define NCAND (MSPLIT * T12)  // 48 rescore candidates per query

typedef float f32x4 __attribute__((ext_vector_type(4)));
typedef float f32x16 __attribute__((ext_vector_type(16)));
typedef short s16x8 __attribute__((ext_vector_type(8)));

__device__ __forceinline__ unsigned short f2bf(float x) {
  unsigned u = __float_as_uint(x);
  return (unsigned short)((u + 0x7fffu + ((u >> 16) & 1u)) >> 16);
}
__device__ __forceinline__ float bf2f(unsigned short h) {
  return __uint_as_float(((unsigned)h) << 16);
}

// ---------------- fused transpose + sq + bf16 split ----------------
__global__ __launch_bounds__(256) void txsq_kernel(
    const float* __restrict__ x, float* __restrict__ xf, float* __restrict__ sq,
    unsigned short* __restrict__ xh, unsigned short* __restrict__ xl) {
  __shared__ float t[96][33];
  int tid = threadIdx.x;
  int b = blockIdx.y;
  int n0 = blockIdx.x * 32;
  const float* xb = x + (size_t)b * C * NPB;
  int tn = tid & 31, tc = tid >> 5;
#pragma unroll
  for (int i = 0; i < 12; i++) {
    int c = tc + i * 8;
    t[c][tn] = xb[(size_t)c * NPB + n0 + tn];
  }
  __syncthreads();
  // phase 2a: xf/xh/xl, item-parallel (768 float4 items, 3 per thread)
#pragma unroll
  for (int k = 0; k < 3; k++) {
    int it = tid + k * 256;
    int nl = it / 24, c4 = it % 24;
    int node = b * NPB + n0 + nl;
    float4 v;
    v.x = t[4 * c4 + 0][nl];
    v.y = t[4 * c4 + 1][nl];
    v.z = t[4 * c4 + 2][nl];
    v.w = t[4 * c4 + 3][nl];
    ushort4 h, l;
    h.x = f2bf(v.x); l.x = f2bf(v.x - bf2f(h.x));
    h.y = f2bf(v.y); l.y = f2bf(v.y - bf2f(h.y));
    h.z = f2bf(v.z); l.z = f2bf(v.z - bf2f(h.z));
    h.w = f2bf(v.w); l.w = f2bf(v.w - bf2f(h.w));
    ((float4*)(xf + (size_t)node * C))[c4] = v;
    ((ushort4*)(xh + (size_t)node * C))[c4] = h;
    ((ushort4*)(xl + (size_t)node * C))[c4] = l;
  }
  // phase 2b: sq, verbatim sequential order (bit-identical to old sqsplit)
  if (tid < 32) {
    int node = b * NPB + n0 + tid;
    float s = 0.f;
#pragma unroll
    for (int i = 0; i < 24; i++) {
      float4 v;
      v.x = t[4 * i + 0][tid];
      v.y = t[4 * i + 1][tid];
      v.z = t[4 * i + 2][tid];
      v.w = t[4 * i + 3][tid];
      s += v.x * v.x + v.y * v.y + v.z * v.z + v.w * v.w;
    }
    sq[node] = s;
  }
}

// ---------------- ONE fused fold launch: block-role dispatch ----------------
__global__ void fold_all_kernel(
    const float* __restrict__ kmap_w, const float* __restrict__ kmap_b,
    const float* __restrict__ kfc_w, const float* __restrict__ kfc_b,
    const float* __restrict__ kmu_w, const float* __restrict__ kmu_b,
    const float* __restrict__ kdec_w, const float* __restrict__ kdec_b,
    const float* __restrict__ ec1_w, const float* __restrict__ ec2_w,
    const float* __restrict__ io_w, const float* __restrict__ io_b,
    const float* __restrict__ fc_w, const float* __restrict__ fc_b,
    const float* __restrict__ up_w, const float* __restrict__ up_b,
    float* __restrict__ WkP, float* __restrict__ bkP, float* __restrict__ WdP,
    float* __restrict__ bdP, float* __restrict__ bPf,
    unsigned short* __restrict__ B1h, unsigned short* __restrict__ B1l,
    unsigned short* __restrict__ B2h, unsigned short* __restrict__ B2l,
    unsigned short* __restrict__ BFh, unsigned short* __restrict__ BFl) {
  __shared__ float sh[4][64];
  int bid = blockIdx.x, tid = threadIdx.x;
  int tx = tid & 63, ty = tid >> 6;
  if (bid < 96) {
    int m = bid;
    float acc = 0.f;
    for (int k = ty; k < 500; k += 4) acc += kmap_w[m * 500 + k] * kfc_w[k * 64 + tx];
    sh[ty][tx] = acc;
    __syncthreads();
    if (ty == 0) WkP[m * 64 + tx] = sh[0][tx] + sh[1][tx] + sh[2][tx] + sh[3][tx];
  } else if (bid == 96) {
    float acc = 0.f;
    for (int k = ty; k < 500; k += 4) acc += kmap_b[k] * kfc_w[k * 64 + tx];
    sh[ty][tx] = acc;
    __syncthreads();
    if (ty == 0) bkP[tx] = sh[0][tx] + sh[1][tx] + sh[2][tx] + sh[3][tx] + kfc_b[tx];
  } else if (bid < 161) {
    int m = bid - 97;
    float acc = 0.f;
    if (tx < 9) {
      for (int k = ty; k < 32; k += 4) acc += kmu_w[m * 32 + k] * kdec_w[k * 9 + tx];
    }
    sh[ty][tx] = acc;
    __syncthreads();
    if (ty == 0 && tx < 9) WdP[m * 9 + tx] = sh[0][tx] + sh[1][tx] + sh[2][tx] + sh[3][tx];
  } else if (bid == 161) {
    float acc = 0.f;
    if (tx < 9) {
      for (int k = ty; k < 32; k += 4) acc += kmu_b[k] * kdec_w[k * 9 + tx];
    }
    sh[ty][tx] = acc;
    __syncthreads();
    if (ty == 0 && tx < 9) bdP[tx] = sh[0][tx] + sh[1][tx] + sh[2][tx] + sh[3][tx] + kdec_b[tx];
  } else if (bid < 234) {
    int t = (bid - 162) * 256 + tid;  // 72*256 = 96*192
    int n = t / 192, k = t % 192;
    float v = ec1_w[(size_t)k * 96 + n];
    if (k < 96) v -= ec1_w[(size_t)(k + 96) * 96 + n];
    unsigned short h = f2bf(v);
    B1h[t] = h;
    B1l[t] = f2bf(v - bf2f(h));
  } else if (bid < 306) {
    int t = (bid - 234) * 256 + tid;
    int n = t / 192, k = t % 192;
    float v = ec2_w[(size_t)k * 96 + n];
    if (k < 96) v -= ec2_w[(size_t)(k + 96) * 96 + n];
    unsigned short h = f2bf(v);
    B2h[t] = h;
    B2l[t] = f2bf(v - bf2f(h));
  } else if (bid < 594) {
    int r = bid - 306;
    int m = r / 3, n = (r % 3) * 64 + tx;
    float acc = 0.f;
    for (int k = ty; k < 192; k += 4) acc += io_w[m * 192 + k] * up_w[(size_t)k * 192 + n];
    sh[ty][tx] = acc;
    __syncthreads();
    if (ty == 0) {
      float v = sh[0][tx] + sh[1][tx] + sh[2][tx] + sh[3][tx];
      unsigned short h = f2bf(v);
      BFh[(size_t)n * 192 + m] = h;
      BFl[(size_t)n * 192 + m] = f2bf(v - bf2f(h));
    }
  } else if (bid < 882) {
    int r = bid - 594;
    int m = r / 3, n = (r % 3) * 64 + tx;
    float acc = 0.f;
    for (int k = ty; k < 192; k += 4)
      acc += fc_w[m * 192 + k] * up_w[(size_t)(192 + k) * 192 + n];
    sh[ty][tx] = acc;
    __syncthreads();
    if (ty == 0) {
      float v = sh[0][tx] + sh[1][tx] + sh[2][tx] + sh[3][tx];
      unsigned short h = f2bf(v);
      BFh[(size_t)n * 192 + 96 + m] = h;
      BFl[(size_t)n * 192 + 96 + m] = f2bf(v - bf2f(h));
    }
  } else {
    if (tid < 192) {
      float acc = up_b[tid];
      for (int k = 0; k < 192; k++) {
        acc += io_b[k] * up_w[k * 192 + tid];
        acc += fc_b[k] * up_w[(192 + k) * 192 + tid];
      }
      bPf[tid] = acc;
    }
  }
}

// ---------------- fused VAE head: h64 = relu(xf@WkP+bkP); argmax9 -> kint, rs ----
__global__ __launch_bounds__(256) void gemmhead_kernel(
    const float* __restrict__ A0, const float* __restrict__ B,
    const float* __restrict__ bias, const float* __restrict__ WdP,
    const float* __restrict__ bdP, int* __restrict__ kint,
    float* __restrict__ rs) {
  __shared__ float As[16][68];
  __shared__ float Bs[16][68];
  __shared__ float hs[64][68];
  __shared__ float wd[576];
  __shared__ float bd[9];
  int tid = threadIdx.x;
  int tx = tid & 15, ty = tid >> 4;
  int row0 = blockIdx.x * 64;
  for (int f = tid; f < 576; f += 256) wd[f] = WdP[f];
  if (tid < 9) bd[tid] = bdP[tid];
  float acc[4][4] = {};
  int ai = tid >> 2;
  int ak = (tid & 3) * 4;
  int bk = tid >> 4;
  int bj = (tid & 15) * 4;

  for (int k0 = 0; k0 < 96; k0 += 16) {
    {
      int r = row0 + ai;
      float4 v = *(const float4*)(A0 + (size_t)r * 96 + k0 + ak);
      As[ak + 0][ai] = v.x;
      As[ak + 1][ai] = v.y;
      As[ak + 2][ai] = v.z;
      As[ak + 3][ai] = v.w;
    }
    {
      int kg = k0 + bk;
      float4 v = *(const float4*)(B + (size_t)kg * 64 + bj);
      *(float4*)&Bs[bk][bj] = v;
    }
    __syncthreads();
#pragma unroll
    for (int kk = 0; kk < 16; kk++) {
      float4 av = *(const float4*)&As[kk][ty * 4];
      float4 bv = *(const float4*)&Bs[kk][tx * 4];
      acc[0][0] += av.x * bv.x; acc[0][1] += av.x * bv.y; acc[0][2] += av.x * bv.z; acc[0][3] += av.x * bv.w;
      acc[1][0] += av.y * bv.x; acc[1][1] += av.y * bv.y; acc[1][2] += av.y * bv.z; acc[1][3] += av.y * bv.w;
      acc[2][0] += av.z * bv.x; acc[2][1] += av.z * bv.y; acc[2][2] += av.z * bv.z; acc[2][3] += av.z * bv.w;
      acc[3][0] += av.w * bv.x; acc[3][1] += av.w * bv.y; acc[3][2] += av.w * bv.z; acc[3][3] += av.w * bv.w;
    }
    __syncthreads();
  }
#pragma unroll
  for (int ii = 0; ii < 4; ii++) {
#pragma unroll
    for (int jj = 0; jj < 4; jj++) {
      int j = tx * 4 + jj;
      hs[ty * 4 + ii][j] = fmaxf(acc[ii][jj] + bias[j], 0.f);
    }
  }
  __syncthreads();
  if (tid < 64) {
    int node = row0 + tid;
    const float4* hp = (const float4*)hs[tid];
    float4 h[16];
#pragma unroll
    for (int i = 0; i < 16; i++) h[i] = hp[i];
    float best = -3.4e38f;
    int bi = 0;
#pragma unroll
    for (int n = 0; n < 9; n++) {
      float a = bd[n];
#pragma unroll
      for (int k = 0; k < 16; k++) {
        float4 hv = h[k];
        a += hv.x * wd[(4 * k + 0) * 9 + n] + hv.y * wd[(4 * k + 1) * 9 + n] +
             hv.z * wd[(4 * k + 2) * 9 + n] + hv.w * wd[(4 * k + 3) * 9 + n];
      }
      if (a > best) { best = a; bi = n; }
    }
    kint[node] = bi;
    rs[node] = (float)bi;
  }
}

// ---------------- branchless top-k helpers (sorting networks) ----------------
__device__ __forceinline__ void ce(float& a, float& b) {
  float lo = fminf(a, b);
  b = fmaxf(a, b);
  a = lo;
}

// Batcher odd-even mergesort, 16 elems, 63 CE, depth 10, ascending
__device__ __forceinline__ void sort16(float* s) {
  // sort8 [0..7]
  ce(s[0], s[1]); ce(s[2], s[3]); ce(s[0], s[2]); ce(s[1], s[3]); ce(s[1], s[2]);
  ce(s[4], s[5]); ce(s[6], s[7]); ce(s[4], s[6]); ce(s[5], s[7]); ce(s[5], s[6]);
  ce(s[0], s[4]); ce(s[1], s[5]); ce(s[2], s[6]); ce(s[3], s[7]);
  ce(s[2], s[4]); ce(s[3], s[5]);
  ce(s[1], s[2]); ce(s[3], s[4]); ce(s[5], s[6]);
  // sort8 [8..15]
  ce(s[8], s[9]); ce(s[10], s[11]); ce(s[8], s[10]); ce(s[9], s[11]); ce(s[9], s[10]);
  ce(s[12], s[13]); ce(s[14], s[15]); ce(s[12], s[14]); ce(s[13], s[15]); ce(s[13], s[14]);
  ce(s[8], s[12]); ce(s[9], s[13]); ce(s[10], s[14]); ce(s[11], s[15]);
  ce(s[10], s[12]); ce(s[11], s[13]);
  ce(s[9], s[10]); ce(s[11], s[12]); ce(s[13], s[14]);
  // odd-even merge of the two sorted 8s
  ce(s[0], s[8]); ce(s[1], s[9]); ce(s[2], s[10]); ce(s[3], s[11]);
  ce(s[4], s[12]); ce(s[5], s[13]); ce(s[6], s[14]); ce(s[7], s[15]);
  ce(s[4], s[8]); ce(s[5], s[9]); ce(s[6], s[10]); ce(s[7], s[11]);
  ce(s[2], s[4]); ce(s[3], s[5]); ce(s[6], s[8]); ce(s[7], s[9]);
  ce(s[10], s[12]); ce(s[11], s[13]);
  ce(s[1], s[2]); ce(s[3], s[4]); ce(s[5], s[6]); ce(s[7], s[8]);
  ce(s[9], s[10]); ce(s[11], s[12]); ce(s[13], s[14]);
}

// fd sorted asc (12), s sorted asc (>=12 used) -> fd = sorted lowest-12 of union.
// 12 min + 20 CE (front-padded bitonic-16 cleanup). Bench-verified (R7).
__device__ __forceinline__ void bmerge12(float* fd, const float* s) {
  float L[12];
#pragma unroll
  for (int i = 0; i < 12; i++) L[i] = fminf(fd[i], s[11 - i]);
  ce(L[0], L[8]); ce(L[1], L[9]); ce(L[2], L[10]); ce(L[3], L[11]);
  ce(L[4], L[8]); ce(L[5], L[9]); ce(L[6], L[10]); ce(L[7], L[11]);
  ce(L[0], L[2]); ce(L[1], L[3]); ce(L[4], L[6]); ce(L[5], L[7]);
  ce(L[8], L[10]); ce(L[9], L[11]);
  ce(L[0], L[1]); ce(L[2], L[3]); ce(L[4], L[5]); ce(L[6], L[7]);
  ce(L[8], L[9]); ce(L[10], L[11]);
#pragma unroll
  for (int i = 0; i < 12; i++) fd[i] = L[i];
}

// ---------------- MFMA kNN filter v9: v7 body + XCD-batch swizzle -------------
__global__ __launch_bounds__(256) void knn_mfma_kernel(
    const unsigned short* __restrict__ xh, const unsigned short* __restrict__ xl,
    const float* __restrict__ sq, int* __restrict__ pk_i) {
  __shared__ __align__(16) float smem_f[6784];  // 27136 B
  unsigned short* mhA = (unsigned short*)smem_f;
  unsigned short* mhB = (unsigned short*)(smem_f + 3328);
  float* sqsA = smem_f + 6656;
  float* sqsB = smem_f + 6720;
  int tid = threadIdx.x;
  int lane = tid & 63, wv = tid >> 6;
  int wm = wv >> 1, wq = wv & 1;
  // XCD-batch swizzle: bid = b + 8*(qb + 49*z)
  int bid = blockIdx.x;
  int b = bid & 7;
  int r = bid >> 3;           // 0..195
  int q0 = (r % 49) * 64;
  int z = r / 49;
  int bbase = b * NPB;
  int t0 = (z * 49) / MSPLIT, t1 = ((z + 1) * 49) / MSPLIT;

  int koff = (lane >> 5) * 8;
  // B-fragments: this wave's 32 queries (fixed across tiles): B[k][q=lane&31]
  int qrow = bbase + q0 + wq * 32 + (lane & 31);
  s16x8 bqh[6], bql[6];
  {
    const unsigned short* ph = xh + (size_t)qrow * 96 + koff;
    const unsigned short* pl = xl + (size_t)qrow * 96 + koff;
#pragma unroll
    for (int kc = 0; kc < 6; kc++) {
      bqh[kc] = *(const s16x8*)(ph + kc * 16);
      bql[kc] = *(const s16x8*)(pl + kc * 16);
    }
  }
  float sqr = sq[qrow];  // this lane's query norm

  float fd[12];
#pragma unroll
  for (int k = 0; k < 12; k++) fd[k] = 3.4e38f;

  // staging: 2 threads/row over 128 rows (2 tiles), 48 shorts per thread
  int srow = tid >> 1;            // 0..127
  int tloc = srow >> 6;           // 0 = tile A, 1 = tile B
  int rrow = srow & 63;
  int sseg = (tid & 1) * 48;      // short offset within row
  int soff = rrow * 104 + sseg;
  unsigned short* mhd = tloc ? mhB : mhA;

  s16x8 st[6];
  float stq = 0.f;
  // prologue: load pair (t0, t0+1), clamped
  {
    int tA = t0 + tloc;
    int ts = (tA < t1) ? tA : (t1 - 1);
    const unsigned short* gh = xh + (size_t)(bbase + ts * 64 + rrow) * 96 + sseg;
#pragma unroll
    for (int i = 0; i < 6; i++) st[i] = *(const s16x8*)(gh + i * 8);
    if (tid < 128) {
      int tq = t0 + (tid >> 6);
      int tqs = (tq < t1) ? tq : (t1 - 1);
      stq = sq[bbase + tqs * 64 + (tid & 63)];
    }
  }

  int sqbase = wm * 32 + 4 * (lane >> 5);
  int mrow = wm * 32 + (lane & 31);
  int np = (t1 - t0 + 1) >> 1;

  for (int p = 0; p < np; p++) {
    int ta = t0 + 2 * p, tb = ta + 1;
    __syncthreads();  // prior iteration's LDS reads complete
#pragma unroll
    for (int i = 0; i < 6; i++) *(s16x8*)(mhd + soff + i * 8) = st[i];
    if (tid < 128) ((tid >> 6) ? sqsB : sqsA)[tid & 63] = stq;
    __syncthreads();

    // issue next-pair loads NOW; latency hides under 2 tiles of MFMA+sort
    {
      int tn = t0 + 2 * (p + 1) + tloc;
      int ts = (tn < t1) ? tn : (t1 - 1);
      const unsigned short* gh = xh + (size_t)(bbase + ts * 64 + rrow) * 96 + sseg;
#pragma unroll
      for (int i = 0; i < 6; i++) st[i] = *(const s16x8*)(gh + i * 8);
      if (tid < 128) {
        int tq = t0 + 2 * (p + 1) + (tid >> 6);
        int tqs = (tq < t1) ? tq : (t1 - 1);
        stq = sq[bbase + tqs * 64 + (tid & 63)];
      }
    }

    // ---- tile A ----
    {
      f32x16 acc = (f32x16){0.f, 0.f, 0.f, 0.f, 0.f, 0.f, 0.f, 0.f,
                            0.f, 0.f, 0.f, 0.f, 0.f, 0.f, 0.f, 0.f};
#pragma unroll
      for (int kc = 0; kc < 6; kc++) {
        s16x8 amh = *(const s16x8*)(mhA + mrow * 104 + kc * 16 + koff);
        acc = __builtin_amdgcn_mfma_f32_32x32x16_bf16(amh, bqh[kc], acc, 0, 0, 0);
        acc = __builtin_amdgcn_mfma_f32_32x32x16_bf16(amh, bql[kc], acc, 0, 0, 0);
      }
      f32x4 sm0 = *(const f32x4*)(sqsA + sqbase);
      f32x4 sm1 = *(const f32x4*)(sqsA + sqbase + 8);
      f32x4 sm2 = *(const f32x4*)(sqsA + sqbase + 16);
      f32x4 sm3 = *(const f32x4*)(sqsA + sqbase + 24);
      int lbase = (ta - t0) * 64;
      float cs[16];
#pragma unroll
      for (int reg = 0; reg < 16; reg++) {
        int g = reg >> 2, e = reg & 3;
        float sqm = (g == 0) ? sm0[e] : (g == 1) ? sm1[e] : (g == 2) ? sm2[e] : sm3[e];
        int mloc = wm * 32 + e + 8 * g + 4 * (lane >> 5);
        float d = fmaf(-2.f, acc[reg], sqr + sqm);
        unsigned u = (__float_as_uint(d) & 0xFFFFFC00u) | (unsigned)(lbase + mloc);
        cs[reg] = __uint_as_float(u);
      }
      sort16(cs);
      bmerge12(fd, cs);
    }
    // ---- tile B (uniform guard: t1 is block-uniform, no barriers inside) ----
    if (tb < t1) {
      f32x16 acc = (f32x16){0.f, 0.f, 0.f, 0.f, 0.f, 0.f, 0.f, 0.f,
                            0.f, 0.f, 0.f, 0.f, 0.f, 0.f, 0.f, 0.f};
#pragma unroll
      for (int kc = 0; kc < 6; kc++) {
        s16x8 amh = *(const s16x8*)(mhB + mrow * 104 + kc * 16 + koff);
        acc = __builtin_amdgcn_mfma_f32_32x32x16_bf16(amh, bqh[kc], acc, 0, 0, 0);
        acc = __builtin_amdgcn_mfma_f32_32x32x16_bf16(amh, bql[kc], acc, 0, 0, 0);
      }
      f32x4 sm0 = *(const f32x4*)(sqsB + sqbase);
      f32x4 sm1 = *(const f32x4*)(sqsB + sqbase + 8);
      f32x4 sm2 = *(const f32x4*)(sqsB + sqbase + 16);
      f32x4 sm3 = *(const f32x4*)(sqsB + sqbase + 24);
      int lbase = (tb - t0) * 64;
      float cs[16];
#pragma unroll
      for (int reg = 0; reg < 16; reg++) {
        int g = reg >> 2, e = reg & 3;
        float sqm = (g == 0) ? sm0[e] : (g == 1) ? sm1[e] : (g == 2) ? sm2[e] : sm3[e];
        int mloc = wm * 32 + e + 8 * g + 4 * (lane >> 5);
        float d = fmaf(-2.f, acc[reg], sqr + sqm);
        unsigned u = (__float_as_uint(d) & 0xFFFFFC00u) | (unsigned)(lbase + mloc);
        cs[reg] = __uint_as_float(u);
      }
      sort16(cs);
      bmerge12(fd, cs);
    }
  }

  // merge 4 sorted partial 12-lists per query via LDS (aliases dead tile A)
  __syncthreads();
  float* cd = smem_f;  // 256 rows x 13 floats = 3328 floats (tile A region)
#pragma unroll
  for (int k = 0; k < 12; k++) cd[(wv * 64 + lane) * 13 + k] = fd[k];
  __syncthreads();
  if (wv == 0) {
    int wva = lane >> 5, ql = lane & 31;
    int ra = wva * 64 + ql, rb = wva * 64 + ql + 32;
    int rc = (wva + 2) * 64 + ql, rd = (wva + 2) * 64 + ql + 32;
    float A[12], B[12];
#pragma unroll
    for (int k = 0; k < 12; k++) { A[k] = cd[ra * 13 + k]; B[k] = cd[rb * 13 + k]; }
    bmerge12(A, B);
    float Cc[12], Dd[12];
#pragma unroll
    for (int k = 0; k < 12; k++) { Cc[k] = cd[rc * 13 + k]; Dd[k] = cd[rd * 13 + k]; }
    bmerge12(Cc, Dd);
    bmerge12(A, Cc);
    size_t base = ((size_t)(bbase + q0 + lane) * MSPLIT + z) * T12;
#pragma unroll
    for (int k = 0; k < T12; k++) {
      int mloc = (int)(__float_as_uint(A[k]) & 0x3FFu) + t0 * 64;
      pk_i[base + k] = bbase + mloc;
    }
  }
}

// ---------------- exact fp32 rescore v4: coop gather + XCD-batch swizzle ------
__global__ __launch_bounds__(256) void rescore_kernel(
    const float* __restrict__ xf, const float* __restrict__ sq,
    const int* __restrict__ pk_i, int* __restrict__ nn) {
  __shared__ float qr[4][96];
  __shared__ float sqq[4];
  int tid = threadIdx.x;
  int qloc = tid >> 6, c = tid & 63;
  int bid = blockIdx.x;
  int qbase = (bid & 7) * NPB + (bid >> 3) * 4;
  for (int f = tid; f < 4 * 96; f += 256)
    qr[f / 96][f % 96] = xf[(size_t)(qbase + f / 96) * 96 + f % 96];
  if (tid < 4) sqq[tid] = sq[qbase + tid];
  __syncthreads();

  int q = qbase + qloc;
  int jv = 0;
  if (c < NCAND) jv = pk_i[(size_t)q * NCAND + c];

  int grp = c >> 3;    // candidate-within-iteration (0..7)
  int chunk = c & 7;   // 12-float chunk of the row (0..7)
  const float4* qp = (const float4*)qr[qloc];
  float4 qv0 = qp[chunk];
  float4 qv1 = qp[chunk + 8];
  float4 qv2 = qp[chunk + 16];

  float dots[6];
#pragma unroll
  for (int it = 0; it < 6; it++) {
    int j = __shfl(jv, it * 8 + grp, 64);
    const float4* mp = (const float4*)(xf + (size_t)j * 96);
    float4 m0 = mp[chunk];
    float4 m1 = mp[chunk + 8];
    float4 m2 = mp[chunk + 16];
    float p = qv0.x * m0.x + qv0.y * m0.y + qv0.z * m0.z + qv0.w * m0.w +
              qv1.x * m1.x + qv1.y * m1.y + qv1.z * m1.z + qv1.w * m1.w +
              qv2.x * m2.x + qv2.y * m2.y + qv2.z * m2.z + qv2.w * m2.w;
    p += __shfl_xor(p, 1, 64);
    p += __shfl_xor(p, 2, 64);
    p += __shfl_xor(p, 4, 64);
    dots[it] = p;
  }

  float g0 = __shfl(dots[0], (c & 7) * 8, 64);
  float g1 = __shfl(dots[1], (c & 7) * 8, 64);
  float g2 = __shfl(dots[2], (c & 7) * 8, 64);
  float g3 = __shfl(dots[3], (c & 7) * 8, 64);
  float g4 = __shfl(dots[4], (c & 7) * 8, 64);
  float g5 = __shfl(dots[5], (c & 7) * 8, 64);
  int itstar = c >> 3;
  float dot = g0;
  dot = (itstar == 1) ? g1 : dot;
  dot = (itstar == 2) ? g2 : dot;
  dot = (itstar == 3) ? g3 : dot;
  dot = (itstar == 4) ? g4 : dot;
  dot = (itstar == 5) ? g5 : dot;

  unsigned long long key = 0xFFFFFFFFFFFFFFFFull;
  if (c < NCAND) {
    float d = (sqq[qloc] - 2.0f * dot) + sq[jv];
    unsigned u = __float_as_uint(d);
    u ^= (u & 0x80000000u) ? 0xFFFFFFFFu : 0x80000000u;
    key = ((unsigned long long)u << 32) | (unsigned)jv;
  }

#pragma unroll
  for (int k = 2; k <= 64; k <<= 1) {
#pragma unroll
    for (int jm = k >> 1; jm >= 1; jm >>= 1) {
      unsigned long long other = __shfl_xor(key, jm, 64);
      bool takeMin = ((c & jm) == 0) == ((c & k) == 0);
      bool sw = (other < key) == takeMin;
      key = sw ? other : key;
    }
  }

  if (c < KNN) {
    nn[(size_t)q * KNN + c] = (int)(unsigned)(key & 0xFFFFFFFFull);
  }
}

// ---------------- fused gather + MFMA EdgeConv GEMM ----------------
// v4: fixed-trip masked gather (R12) + acc1 hoist + XCD-batch swizzle.
__global__ __launch_bounds__(192) void mfma_ec_fused_kernel(
    const unsigned short* __restrict__ A0h, const unsigned short* __restrict__ A0l,
    const float* __restrict__ feat32, const unsigned short* __restrict__ gfh,
    const unsigned short* __restrict__ gfl, int mode,
    const int* __restrict__ nn, const int* __restrict__ kint,
    const unsigned short* __restrict__ Bth, const unsigned short* __restrict__ Btl,
    const float* __restrict__ rs, const float* __restrict__ bias, int relu,
    unsigned short* __restrict__ Oh, unsigned short* __restrict__ Ol) {
  __shared__ float rsL[32];
  __shared__ float bL[96];
  __shared__ __align__(16) unsigned short Sth[32][104];
  __shared__ __align__(16) unsigned short Stl[32][104];
  int tid = threadIdx.x, lane = tid & 63, wv = tid >> 6;
  int bid = blockIdx.x;
  int m0 = (bid & 7) * NPB + (bid >> 3) * 32;  // XCD-batch swizzle
  if (tid < 32) rsL[tid] = rs[m0 + tid];
  if (tid < 96) bL[tid] = bias[tid];

  for (int it = tid; it < 768; it += 192) {
    int nl = it / 24, c4 = it % 24;
    int node = m0 + nl;
    int kc = kint[node];
    const int* nr = nn + (size_t)node * KNN;
    int jj[KNN];
#pragma unroll
    for (int k = 0; k < KNN; k++) jj[k] = nr[k];
    float4 acc = make_float4(0.f, 0.f, 0.f, 0.f);
    if (mode == 0) {
#pragma unroll
      for (int k = 0; k < KNN; k++) {
        float4 v = ((const float4*)(feat32 + (size_t)jj[k] * C))[c4];
        bool on = (k < kc);
        acc.x = on ? acc.x + v.x : acc.x;
        acc.y = on ? acc.y + v.y : acc.y;
        acc.z = on ? acc.z + v.z : acc.z;
        acc.w = on ? acc.w + v.w : acc.w;
      }
    } else {
#pragma unroll
      for (int k = 0; k < KNN; k++) {
        ushort4 h = ((const ushort4*)(gfh + (size_t)jj[k] * C))[c4];
        ushort4 l = ((const ushort4*)(gfl + (size_t)jj[k] * C))[c4];
        bool on = (k < kc);
        acc.x = on ? acc.x + bf2f(h.x) + bf2f(l.x) : acc.x;
        acc.y = on ? acc.y + bf2f(h.y) + bf2f(l.y) : acc.y;
        acc.z = on ? acc.z + bf2f(h.z) + bf2f(l.z) : acc.z;
        acc.w = on ? acc.w + bf2f(h.w) + bf2f(l.w) : acc.w;
      }
    }
    ushort4 h, l;
    h.x = f2bf(acc.x); l.x = f2bf(acc.x - bf2f(h.x));
    h.y = f2bf(acc.y); l.y = f2bf(acc.y - bf2f(h.y));
    h.z = f2bf(acc.z); l.z = f2bf(acc.z - bf2f(h.z));
    h.w = f2bf(acc.w); l.w = f2bf(acc.w - bf2f(h.w));
    *(ushort4*)&Sth[nl][c4 * 4] = h;
    *(ushort4*)&Stl[nl][c4 * 4] = l;
  }

  int koff = (lane >> 5) * 8;
  int arow = m0 + (lane & 31);
  const unsigned short* a0h = A0h + (size_t)arow * 96 + koff;
  const unsigned short* a0l = A0l + (size_t)arow * 96 + koff;
  int rloc = lane & 31;
  int n = wv * 32 + (lane & 31);

  f32x16 acc1 = (f32x16){0.f, 0.f, 0.f, 0.f, 0.f, 0.f, 0.f, 0.f,
                         0.f, 0.f, 0.f, 0.f, 0.f, 0.f, 0.f, 0.f};
  f32x16 acc2 = acc1;

#pragma unroll
  for (int c = 0; c < 6; c++) {
    s16x8 ah = *(const s16x8*)(a0h + c * 16);
    s16x8 al = *(const s16x8*)(a0l + c * 16);
    size_t bo = (size_t)n * 192 + c * 16 + koff;
    s16x8 bh = *(const s16x8*)(Bth + bo);
    s16x8 bl = *(const s16x8*)(Btl + bo);
    acc1 = __builtin_amdgcn_mfma_f32_32x32x16_bf16(ah, bh, acc1, 0, 0, 0);
    acc1 = __builtin_amdgcn_mfma_f32_32x32x16_bf16(al, bh, acc1, 0, 0, 0);
    acc1 = __builtin_amdgcn_mfma_f32_32x32x16_bf16(ah, bl, acc1, 0, 0, 0);
  }
  __syncthreads();

#pragma unroll
  for (int c = 6; c < 12; c++) {
    s16x8 ah = *(const s16x8*)(&Sth[rloc][(c - 6) * 16 + koff]);
    s16x8 al = *(const s16x8*)(&Stl[rloc][(c - 6) * 16 + koff]);
    size_t bo = (size_t)n * 192 + c * 16 + koff;
    s16x8 bh = *(const s16x8*)(Bth + bo);
    s16x8 bl = *(const s16x8*)(Btl + bo);
    acc2 = __builtin_amdgcn_mfma_f32_32x32x16_bf16(ah, bh, acc2, 0, 0, 0);
    acc2 = __builtin_amdgcn_mfma_f32_32x32x16_bf16(al, bh, acc2, 0, 0, 0);
    acc2 = __builtin_amdgcn_mfma_f32_32x32x16_bf16(ah, bl, acc2, 0, 0, 0);
  }

  float bn = bL[n];
#pragma unroll
  for (int reg = 0; reg < 16; reg++) {
    int rl = (reg & 3) + 8 * (reg >> 2) + 4 * (lane >> 5);
    int r = m0 + rl;
    float v = rsL[rl] * (acc1[reg] + bn) + acc2[reg];
    if (relu) v = fmaxf(v, 0.f);
    unsigned short h = f2bf(v);
    Oh[(size_t)r * 96 + n] = h;
    Ol[(size_t)r * 96 + n] = f2bf(v - bf2f(h));
  }
}

// ---------------- MFMA final GEMM + transpose-store: grid 784, block 384 ------
// v2: 6 waves cover all 192 output cols in ONE block (was grid (784,2) x 3
// waves): A-fragments read once per row-tile, half the blocks/prologues.
// Per-(row,col) MFMA operands/order and store addresses identical -> output
// bit-identical. tt is per-wave (wave-local s_waitcnt trick preserved).
__global__ __launch_bounds__(384) void mfma_final_kernel(
    const unsigned short* __restrict__ A0h, const unsigned short* __restrict__ A0l,
    const unsigned short* __restrict__ A1h, const unsigned short* __restrict__ A1l,
    const unsigned short* __restrict__ Bth, const unsigned short* __restrict__ Btl,
    const float* __restrict__ bias, float* __restrict__ out) {
  __shared__ float bL[192];
  __shared__ float tt[6][32][33];
  int tid = threadIdx.x, lane = tid & 63, wv = tid >> 6;  // wv 0..5
  int bid = blockIdx.x;
  int m0 = (bid & 7) * NPB + (bid >> 3) * 32;  // XCD-batch swizzle
  if (tid < 192) bL[tid] = bias[tid];
  __syncthreads();

  int koff = (lane >> 5) * 8;
  int arow = m0 + (lane & 31);
  const unsigned short* a0h = A0h + (size_t)arow * 96 + koff;
  const unsigned short* a0l = A0l + (size_t)arow * 96 + koff;
  const unsigned short* a1h = A1h + (size_t)arow * 96 + koff;
  const unsigned short* a1l = A1l + (size_t)arow * 96 + koff;
  int nloc = lane & 31;
  int n = wv * 32 + nloc;  // 0..191

  f32x16 acc = (f32x16){0.f, 0.f, 0.f, 0.f, 0.f, 0.f, 0.f, 0.f,
                        0.f, 0.f, 0.f, 0.f, 0.f, 0.f, 0.f, 0.f};
#pragma unroll
  for (int c = 0; c < 12; c++) {
    s16x8 ah, al;
    if (c < 6) {
      ah = *(const s16x8*)(a0h + c * 16);
      al = *(const s16x8*)(a0l + c * 16);
    } else {
      ah = *(const s16x8*)(a1h + (c - 6) * 16);
      al = *(const s16x8*)(a1l + (c - 6) * 16);
    }
    size_t bo = (size_t)n * 192 + c * 16 + koff;
    s16x8 bh = *(const s16x8*)(Bth + bo);
    s16x8 bl = *(const s16x8*)(Btl + bo);
    acc = __builtin_amdgcn_mfma_f32_32x32x16_bf16(ah, bh, acc, 0, 0, 0);
    acc = __builtin_amdgcn_mfma_f32_32x32x16_bf16(al, bh, acc, 0, 0, 0);
    acc = __builtin_amdgcn_mfma_f32_32x32x16_bf16(ah, bl, acc, 0, 0, 0);
  }

  float bn = bL[n];
#pragma unroll
  for (int reg = 0; reg < 16; reg++) {
    int rl = (reg & 3) + 8 * (reg >> 2) + 4 * (lane >> 5);
    tt[wv][nloc][rl] = fmaxf(acc[reg] + bn, 0.f);
  }
  __builtin_amdgcn_s_waitcnt(0);  // wave-local LDS write->read (R12-proven)
  int gbase = m0 + nloc;  // 32-row tile lies within one batch (3136 % 32 == 0)
  int bb = gbase / NPB, nidx = gbase % NPB;
#pragma unroll
  for (int i = 0; i < 16; i++) {
    int nl = 2 * i + (lane >> 5);
    float v = tt[wv][nl][nloc];
    int ng = wv * 32 + nl;
    out[(size_t)bb * COUT * NPB + (size_t)ng * NPB + nidx] = v;
  }
}

extern "C" void kernel_launch(void* const* d_in, const int* in_sizes, int n_in,
                              void* d_out, int out_size, void* d_ws, size_t ws_size,
                              hipStream_t stream) {
  const float* x      = (const float*)d_in[0];
  const float* kmap_w = (const float*)d_in[1];
  const float* kmap_b = (const float*)d_in[2];
  const float* kfc_w  = (const float*)d_in[3];
  const float* kfc_b  = (const float*)d_in[4];
  const float* kmu_w  = (const float*)d_in[5];
  const float* kmu_b  = (const float*)d_in[6];
  const float* kdec_w = (const float*)d_in[7];
  const float* kdec_b = (const float*)d_in[8];
  const float* ec1_w  = (const float*)d_in[9];
  const float* ec1_b  = (const float*)d_in[10];
  const float* ec2_w  = (const float*)d_in[11];
  const float* ec2_b  = (const float*)d_in[12];
  const float* fc_w   = (const float*)d_in[13];
  const float* fc_b   = (const float*)d_in[14];
  const float* io_w   = (const float*)d_in[15];
  const float* io_b   = (const float*)d_in[16];
  const float* up_w   = (const float*)d_in[17];
  const float* up_b   = (const float*)d_in[18];

  // ---- workspace layout (liveness-aliased) ----
  char* ws = (char*)d_ws;
  size_t off = 0;
  auto alloc = [&](size_t bytes) -> void* {
    void* p = ws + off;
    off += (bytes + 255) & ~(size_t)255;
    return p;
  };
  const size_t HBF = (size_t)NODES * C * 2;  // bf16 plane (256-aligned)
  float* xf   = (float*)alloc((size_t)NODES * C * 4);
  float* sqb  = (float*)alloc((size_t)NODES * 4);
  float* rs   = (float*)alloc((size_t)NODES * 4);
  int*   kint = (int*)alloc((size_t)NODES * 4);
  int*   nn   = (int*)alloc((size_t)NODES * KNN * 4);
  unsigned short* xh = (unsigned short*)alloc(HBF);
  unsigned short* xl = (unsigned short*)alloc(HBF);
  char* region = (char*)alloc((size_t)NODES * COUT * 4);
  // region timeline: pk_i(4.8M) -> h1 pair -> h2 pair (serial)
  int*   pk_i   = (int*)region;
  unsigned short* h1h = (unsigned short*)region;
  unsigned short* h1l = (unsigned short*)(region + HBF);
  unsigned short* h2h = (unsigned short*)(region + 2 * HBF);
  unsigned short* h2l = (unsigned short*)(region + 3 * HBF);
  float* WkP = (float*)alloc(96 * 64 * 4);
  float* bkP = (float*)alloc(64 * 4);
  float* WdP = (float*)alloc(64 * 9 * 4);
  float* bdP = (float*)alloc(16 * 4);
  float* bPf = (float*)alloc(192 * 4);
  unsigned short* B1h = (unsigned short*)alloc(96 * 192 * 2);
  unsigned short* B1l = (unsigned short*)alloc(96 * 192 * 2);
  unsigned short* B2h = (unsigned short*)alloc(96 * 192 * 2);
  unsigned short* B2l = (unsigned short*)alloc(96 * 192 * 2);
  unsigned short* BFh = (unsigned short*)alloc(192 * 192 * 2);
  unsigned short* BFl = (unsigned short*)alloc(192 * 192 * 2);

  // ---- fused transpose + sq + bf16 split ----
  txsq_kernel<<<dim3(98, 8), 256, 0, stream>>>(x, xf, sqb, xh, xl);

  // ---- one fused fold launch ----
  fold_all_kernel<<<883, 256, 0, stream>>>(
      kmap_w, kmap_b, kfc_w, kfc_b, kmu_w, kmu_b, kdec_w, kdec_b, ec1_w, ec2_w,
      io_w, io_b, fc_w, fc_b, up_w, up_b,
      WkP, bkP, WdP, bdP, bPf, B1h, B1l, B2h, B2l, BFh, BFl);

  // ---- fused VAE head: h64 GEMM + argmax -> kint, rs ----
  gemmhead_kernel<<<392, 256, 0, stream>>>(xf, WkP, bkP, WdP, bdP, kint, rs);

  // ---- kNN filter (v9) + exact rescore (both XCD-batch swizzled) ----
  knn_mfma_kernel<<<1568, 256, 0, stream>>>(xh, xl, sqb, pk_i);
  rescore_kernel<<<6272, 256, 0, stream>>>(xf, sqb, pk_i, nn);

  // ---- EdgeConv layer 1 (relu), gather fused (XCD-batch swizzled) ----
  mfma_ec_fused_kernel<<<784, 192, 0, stream>>>(
      xh, xl, xf, (const unsigned short*)nullptr, (const unsigned short*)nullptr,
      0, nn, kint, B1h, B1l, rs, ec1_b, 1, h1h, h1l);
  // ---- EdgeConv layer 2 (no relu), gather fused ----
  mfma_ec_fused_kernel<<<784, 192, 0, stream>>>(
      h1h, h1l, (const float*)nullptr, h1h, h1l,
      1, nn, kint, B2h, B2l, rs, ec2_b, 0, h2h, h2l);
  // ---- final folded GEMM + transpose-store (6-wave, all 192 cols/block) ----
  mfma_final_kernel<<<784, 384, 0, stream>>>(xh, xl, h2h, h2l, BFh, BFl,
                                             bPf, (float*)d_out);
}

// Round 16
// 315.767 us; speedup vs baseline: 1.0104x; 1.0104x over previous
//
#include <hip/hip_runtime.h>

#define NODES 25088
#define NB 8
#define NPB 3136   // nodes per batch (56*56)
#define C 96
#define KNN 9
#define COUT 192
#define MSPLIT 4   // m-range quarters for knn filter
#define T12 12     // rescore depth per quarter (output)
#define NCAND (MSPLIT * T12)  // 48 rescore candidates per query

typedef float f32x4 __attribute__((ext_vector_type(4)));
typedef float f32x16 __attribute__((ext_vector_type(16)));
typedef short s16x8 __attribute__((ext_vector_type(8)));

__device__ __forceinline__ unsigned short f2bf(float x) {
  unsigned u = __float_as_uint(x);
  return (unsigned short)((u + 0x7fffu + ((u >> 16) & 1u)) >> 16);
}
__device__ __forceinline__ float bf2f(unsigned short h) {
  return __uint_as_float(((unsigned)h) << 16);
}

// ---------------- fused transpose + sq + bf16 split ----------------
__global__ __launch_bounds__(256) void txsq_kernel(
    const float* __restrict__ x, float* __restrict__ xf, float* __restrict__ sq,
    unsigned short* __restrict__ xh, unsigned short* __restrict__ xl) {
  __shared__ float t[96][33];
  int tid = threadIdx.x;
  int b = blockIdx.y;
  int n0 = blockIdx.x * 32;
  const float* xb = x + (size_t)b * C * NPB;
  int tn = tid & 31, tc = tid >> 5;
#pragma unroll
  for (int i = 0; i < 12; i++) {
    int c = tc + i * 8;
    t[c][tn] = xb[(size_t)c * NPB + n0 + tn];
  }
  __syncthreads();
  // phase 2a: xf/xh/xl, item-parallel (768 float4 items, 3 per thread)
#pragma unroll
  for (int k = 0; k < 3; k++) {
    int it = tid + k * 256;
    int nl = it / 24, c4 = it % 24;
    int node = b * NPB + n0 + nl;
    float4 v;
    v.x = t[4 * c4 + 0][nl];
    v.y = t[4 * c4 + 1][nl];
    v.z = t[4 * c4 + 2][nl];
    v.w = t[4 * c4 + 3][nl];
    ushort4 h, l;
    h.x = f2bf(v.x); l.x = f2bf(v.x - bf2f(h.x));
    h.y = f2bf(v.y); l.y = f2bf(v.y - bf2f(h.y));
    h.z = f2bf(v.z); l.z = f2bf(v.z - bf2f(h.z));
    h.w = f2bf(v.w); l.w = f2bf(v.w - bf2f(h.w));
    ((float4*)(xf + (size_t)node * C))[c4] = v;
    ((ushort4*)(xh + (size_t)node * C))[c4] = h;
    ((ushort4*)(xl + (size_t)node * C))[c4] = l;
  }
  // phase 2b: sq, verbatim sequential order (bit-identical to old sqsplit)
  if (tid < 32) {
    int node = b * NPB + n0 + tid;
    float s = 0.f;
#pragma unroll
    for (int i = 0; i < 24; i++) {
      float4 v;
      v.x = t[4 * i + 0][tid];
      v.y = t[4 * i + 1][tid];
      v.z = t[4 * i + 2][tid];
      v.w = t[4 * i + 3][tid];
      s += v.x * v.x + v.y * v.y + v.z * v.z + v.w * v.w;
    }
    sq[node] = s;
  }
}

// ---------------- ONE fused fold launch: block-role dispatch ----------------
__global__ void fold_all_kernel(
    const float* __restrict__ kmap_w, const float* __restrict__ kmap_b,
    const float* __restrict__ kfc_w, const float* __restrict__ kfc_b,
    const float* __restrict__ kmu_w, const float* __restrict__ kmu_b,
    const float* __restrict__ kdec_w, const float* __restrict__ kdec_b,
    const float* __restrict__ ec1_w, const float* __restrict__ ec2_w,
    const float* __restrict__ io_w, const float* __restrict__ io_b,
    const float* __restrict__ fc_w, const float* __restrict__ fc_b,
    const float* __restrict__ up_w, const float* __restrict__ up_b,
    float* __restrict__ WkP, float* __restrict__ bkP, float* __restrict__ WdP,
    float* __restrict__ bdP, float* __restrict__ bPf,
    unsigned short* __restrict__ B1h, unsigned short* __restrict__ B1l,
    unsigned short* __restrict__ B2h, unsigned short* __restrict__ B2l,
    unsigned short* __restrict__ BFh, unsigned short* __restrict__ BFl) {
  __shared__ float sh[4][64];
  int bid = blockIdx.x, tid = threadIdx.x;
  int tx = tid & 63, ty = tid >> 6;
  if (bid < 96) {
    int m = bid;
    float acc = 0.f;
    for (int k = ty; k < 500; k += 4) acc += kmap_w[m * 500 + k] * kfc_w[k * 64 + tx];
    sh[ty][tx] = acc;
    __syncthreads();
    if (ty == 0) WkP[m * 64 + tx] = sh[0][tx] + sh[1][tx] + sh[2][tx] + sh[3][tx];
  } else if (bid == 96) {
    float acc = 0.f;
    for (int k = ty; k < 500; k += 4) acc += kmap_b[k] * kfc_w[k * 64 + tx];
    sh[ty][tx] = acc;
    __syncthreads();
    if (ty == 0) bkP[tx] = sh[0][tx] + sh[1][tx] + sh[2][tx] + sh[3][tx] + kfc_b[tx];
  } else if (bid < 161) {
    int m = bid - 97;
    float acc = 0.f;
    if (tx < 9) {
      for (int k = ty; k < 32; k += 4) acc += kmu_w[m * 32 + k] * kdec_w[k * 9 + tx];
    }
    sh[ty][tx] = acc;
    __syncthreads();
    if (ty == 0 && tx < 9) WdP[m * 9 + tx] = sh[0][tx] + sh[1][tx] + sh[2][tx] + sh[3][tx];
  } else if (bid == 161) {
    float acc = 0.f;
    if (tx < 9) {
      for (int k = ty; k < 32; k += 4) acc += kmu_b[k] * kdec_w[k * 9 + tx];
    }
    sh[ty][tx] = acc;
    __syncthreads();
    if (ty == 0 && tx < 9) bdP[tx] = sh[0][tx] + sh[1][tx] + sh[2][tx] + sh[3][tx] + kdec_b[tx];
  } else if (bid < 234) {
    int t = (bid - 162) * 256 + tid;  // 72*256 = 96*192
    int n = t / 192, k = t % 192;
    float v = ec1_w[(size_t)k * 96 + n];
    if (k < 96) v -= ec1_w[(size_t)(k + 96) * 96 + n];
    unsigned short h = f2bf(v);
    B1h[t] = h;
    B1l[t] = f2bf(v - bf2f(h));
  } else if (bid < 306) {
    int t = (bid - 234) * 256 + tid;
    int n = t / 192, k = t % 192;
    float v = ec2_w[(size_t)k * 96 + n];
    if (k < 96) v -= ec2_w[(size_t)(k + 96) * 96 + n];
    unsigned short h = f2bf(v);
    B2h[t] = h;
    B2l[t] = f2bf(v - bf2f(h));
  } else if (bid < 594) {
    int r = bid - 306;
    int m = r / 3, n = (r % 3) * 64 + tx;
    float acc = 0.f;
    for (int k = ty; k < 192; k += 4) acc += io_w[m * 192 + k] * up_w[(size_t)k * 192 + n];
    sh[ty][tx] = acc;
    __syncthreads();
    if (ty == 0) {
      float v = sh[0][tx] + sh[1][tx] + sh[2][tx] + sh[3][tx];
      unsigned short h = f2bf(v);
      BFh[(size_t)n * 192 + m] = h;
      BFl[(size_t)n * 192 + m] = f2bf(v - bf2f(h));
    }
  } else if (bid < 882) {
    int r = bid - 594;
    int m = r / 3, n = (r % 3) * 64 + tx;
    float acc = 0.f;
    for (int k = ty; k < 192; k += 4)
      acc += fc_w[m * 192 + k] * up_w[(size_t)(192 + k) * 192 + n];
    sh[ty][tx] = acc;
    __syncthreads();
    if (ty == 0) {
      float v = sh[0][tx] + sh[1][tx] + sh[2][tx] + sh[3][tx];
      unsigned short h = f2bf(v);
      BFh[(size_t)n * 192 + 96 + m] = h;
      BFl[(size_t)n * 192 + 96 + m] = f2bf(v - bf2f(h));
    }
  } else {
    if (tid < 192) {
      float acc = up_b[tid];
      for (int k = 0; k < 192; k++) {
        acc += io_b[k] * up_w[k * 192 + tid];
        acc += fc_b[k] * up_w[(192 + k) * 192 + tid];
      }
      bPf[tid] = acc;
    }
  }
}

// ---------------- fused VAE head: h64 = relu(xf@WkP+bkP); argmax9 -> kint, rs ----
__global__ __launch_bounds__(256) void gemmhead_kernel(
    const float* __restrict__ A0, const float* __restrict__ B,
    const float* __restrict__ bias, const float* __restrict__ WdP,
    const float* __restrict__ bdP, int* __restrict__ kint,
    float* __restrict__ rs) {
  __shared__ float As[16][68];
  __shared__ float Bs[16][68];
  __shared__ float hs[64][68];
  __shared__ float wd[576];
  __shared__ float bd[9];
  int tid = threadIdx.x;
  int tx = tid & 15, ty = tid >> 4;
  int row0 = blockIdx.x * 64;
  for (int f = tid; f < 576; f += 256) wd[f] = WdP[f];
  if (tid < 9) bd[tid] = bdP[tid];
  float acc[4][4] = {};
  int ai = tid >> 2;
  int ak = (tid & 3) * 4;
  int bk = tid >> 4;
  int bj = (tid & 15) * 4;

  for (int k0 = 0; k0 < 96; k0 += 16) {
    {
      int r = row0 + ai;
      float4 v = *(const float4*)(A0 + (size_t)r * 96 + k0 + ak);
      As[ak + 0][ai] = v.x;
      As[ak + 1][ai] = v.y;
      As[ak + 2][ai] = v.z;
      As[ak + 3][ai] = v.w;
    }
    {
      int kg = k0 + bk;
      float4 v = *(const float4*)(B + (size_t)kg * 64 + bj);
      *(float4*)&Bs[bk][bj] = v;
    }
    __syncthreads();
#pragma unroll
    for (int kk = 0; kk < 16; kk++) {
      float4 av = *(const float4*)&As[kk][ty * 4];
      float4 bv = *(const float4*)&Bs[kk][tx * 4];
      acc[0][0] += av.x * bv.x; acc[0][1] += av.x * bv.y; acc[0][2] += av.x * bv.z; acc[0][3] += av.x * bv.w;
      acc[1][0] += av.y * bv.x; acc[1][1] += av.y * bv.y; acc[1][2] += av.y * bv.z; acc[1][3] += av.y * bv.w;
      acc[2][0] += av.z * bv.x; acc[2][1] += av.z * bv.y; acc[2][2] += av.z * bv.z; acc[2][3] += av.z * bv.w;
      acc[3][0] += av.w * bv.x; acc[3][1] += av.w * bv.y; acc[3][2] += av.w * bv.z; acc[3][3] += av.w * bv.w;
    }
    __syncthreads();
  }
#pragma unroll
  for (int ii = 0; ii < 4; ii++) {
#pragma unroll
    for (int jj = 0; jj < 4; jj++) {
      int j = tx * 4 + jj;
      hs[ty * 4 + ii][j] = fmaxf(acc[ii][jj] + bias[j], 0.f);
    }
  }
  __syncthreads();
  if (tid < 64) {
    int node = row0 + tid;
    const float4* hp = (const float4*)hs[tid];
    float4 h[16];
#pragma unroll
    for (int i = 0; i < 16; i++) h[i] = hp[i];
    float best = -3.4e38f;
    int bi = 0;
#pragma unroll
    for (int n = 0; n < 9; n++) {
      float a = bd[n];
#pragma unroll
      for (int k = 0; k < 16; k++) {
        float4 hv = h[k];
        a += hv.x * wd[(4 * k + 0) * 9 + n] + hv.y * wd[(4 * k + 1) * 9 + n] +
             hv.z * wd[(4 * k + 2) * 9 + n] + hv.w * wd[(4 * k + 3) * 9 + n];
      }
      if (a > best) { best = a; bi = n; }
    }
    kint[node] = bi;
    rs[node] = (float)bi;
  }
}

// ---------------- branchless top-k helpers (sorting networks) ----------------
__device__ __forceinline__ void ce(float& a, float& b) {
  float lo = fminf(a, b);
  b = fmaxf(a, b);
  a = lo;
}

// Batcher odd-even mergesort, 16 elems, 63 CE, depth 10, ascending
__device__ __forceinline__ void sort16(float* s) {
  // sort8 [0..7]
  ce(s[0], s[1]); ce(s[2], s[3]); ce(s[0], s[2]); ce(s[1], s[3]); ce(s[1], s[2]);
  ce(s[4], s[5]); ce(s[6], s[7]); ce(s[4], s[6]); ce(s[5], s[7]); ce(s[5], s[6]);
  ce(s[0], s[4]); ce(s[1], s[5]); ce(s[2], s[6]); ce(s[3], s[7]);
  ce(s[2], s[4]); ce(s[3], s[5]);
  ce(s[1], s[2]); ce(s[3], s[4]); ce(s[5], s[6]);
  // sort8 [8..15]
  ce(s[8], s[9]); ce(s[10], s[11]); ce(s[8], s[10]); ce(s[9], s[11]); ce(s[9], s[10]);
  ce(s[12], s[13]); ce(s[14], s[15]); ce(s[12], s[14]); ce(s[13], s[15]); ce(s[13], s[14]);
  ce(s[8], s[12]); ce(s[9], s[13]); ce(s[10], s[14]); ce(s[11], s[15]);
  ce(s[10], s[12]); ce(s[11], s[13]);
  ce(s[9], s[10]); ce(s[11], s[12]); ce(s[13], s[14]);
  // odd-even merge of the two sorted 8s
  ce(s[0], s[8]); ce(s[1], s[9]); ce(s[2], s[10]); ce(s[3], s[11]);
  ce(s[4], s[12]); ce(s[5], s[13]); ce(s[6], s[14]); ce(s[7], s[15]);
  ce(s[4], s[8]); ce(s[5], s[9]); ce(s[6], s[10]); ce(s[7], s[11]);
  ce(s[2], s[4]); ce(s[3], s[5]); ce(s[6], s[8]); ce(s[7], s[9]);
  ce(s[10], s[12]); ce(s[11], s[13]);
  ce(s[1], s[2]); ce(s[3], s[4]); ce(s[5], s[6]); ce(s[7], s[8]);
  ce(s[9], s[10]); ce(s[11], s[12]); ce(s[13], s[14]);
}

// fd sorted asc (12), s sorted asc (>=12 used) -> fd = sorted lowest-12 of union.
// 12 min + 20 CE (front-padded bitonic-16 cleanup). Bench-verified (R7).
__device__ __forceinline__ void bmerge12(float* fd, const float* s) {
  float L[12];
#pragma unroll
  for (int i = 0; i < 12; i++) L[i] = fminf(fd[i], s[11 - i]);
  ce(L[0], L[8]); ce(L[1], L[9]); ce(L[2], L[10]); ce(L[3], L[11]);
  ce(L[4], L[8]); ce(L[5], L[9]); ce(L[6], L[10]); ce(L[7], L[11]);
  ce(L[0], L[2]); ce(L[1], L[3]); ce(L[4], L[6]); ce(L[5], L[7]);
  ce(L[8], L[10]); ce(L[9], L[11]);
  ce(L[0], L[1]); ce(L[2], L[3]); ce(L[4], L[5]); ce(L[6], L[7]);
  ce(L[8], L[9]); ce(L[10], L[11]);
#pragma unroll
  for (int i = 0; i < 12; i++) fd[i] = L[i];
}

// ---------------- MFMA kNN filter v9: v7 body + XCD-batch swizzle -------------
__global__ __launch_bounds__(256) void knn_mfma_kernel(
    const unsigned short* __restrict__ xh, const unsigned short* __restrict__ xl,
    const float* __restrict__ sq, int* __restrict__ pk_i) {
  __shared__ __align__(16) float smem_f[6784];  // 27136 B
  unsigned short* mhA = (unsigned short*)smem_f;
  unsigned short* mhB = (unsigned short*)(smem_f + 3328);
  float* sqsA = smem_f + 6656;
  float* sqsB = smem_f + 6720;
  int tid = threadIdx.x;
  int lane = tid & 63, wv = tid >> 6;
  int wm = wv >> 1, wq = wv & 1;
  // XCD-batch swizzle: bid = b + 8*(qb + 49*z)
  int bid = blockIdx.x;
  int b = bid & 7;
  int r = bid >> 3;           // 0..195
  int q0 = (r % 49) * 64;
  int z = r / 49;
  int bbase = b * NPB;
  int t0 = (z * 49) / MSPLIT, t1 = ((z + 1) * 49) / MSPLIT;

  int koff = (lane >> 5) * 8;
  // B-fragments: this wave's 32 queries (fixed across tiles): B[k][q=lane&31]
  int qrow = bbase + q0 + wq * 32 + (lane & 31);
  s16x8 bqh[6], bql[6];
  {
    const unsigned short* ph = xh + (size_t)qrow * 96 + koff;
    const unsigned short* pl = xl + (size_t)qrow * 96 + koff;
#pragma unroll
    for (int kc = 0; kc < 6; kc++) {
      bqh[kc] = *(const s16x8*)(ph + kc * 16);
      bql[kc] = *(const s16x8*)(pl + kc * 16);
    }
  }
  float sqr = sq[qrow];  // this lane's query norm

  float fd[12];
#pragma unroll
  for (int k = 0; k < 12; k++) fd[k] = 3.4e38f;

  // staging: 2 threads/row over 128 rows (2 tiles), 48 shorts per thread
  int srow = tid >> 1;            // 0..127
  int tloc = srow >> 6;           // 0 = tile A, 1 = tile B
  int rrow = srow & 63;
  int sseg = (tid & 1) * 48;      // short offset within row
  int soff = rrow * 104 + sseg;
  unsigned short* mhd = tloc ? mhB : mhA;

  s16x8 st[6];
  float stq = 0.f;
  // prologue: load pair (t0, t0+1), clamped
  {
    int tA = t0 + tloc;
    int ts = (tA < t1) ? tA : (t1 - 1);
    const unsigned short* gh = xh + (size_t)(bbase + ts * 64 + rrow) * 96 + sseg;
#pragma unroll
    for (int i = 0; i < 6; i++) st[i] = *(const s16x8*)(gh + i * 8);
    if (tid < 128) {
      int tq = t0 + (tid >> 6);
      int tqs = (tq < t1) ? tq : (t1 - 1);
      stq = sq[bbase + tqs * 64 + (tid & 63)];
    }
  }

  int sqbase = wm * 32 + 4 * (lane >> 5);
  int mrow = wm * 32 + (lane & 31);
  int np = (t1 - t0 + 1) >> 1;

  for (int p = 0; p < np; p++) {
    int ta = t0 + 2 * p, tb = ta + 1;
    __syncthreads();  // prior iteration's LDS reads complete
#pragma unroll
    for (int i = 0; i < 6; i++) *(s16x8*)(mhd + soff + i * 8) = st[i];
    if (tid < 128) ((tid >> 6) ? sqsB : sqsA)[tid & 63] = stq;
    __syncthreads();

    // issue next-pair loads NOW; latency hides under 2 tiles of MFMA+sort
    {
      int tn = t0 + 2 * (p + 1) + tloc;
      int ts = (tn < t1) ? tn : (t1 - 1);
      const unsigned short* gh = xh + (size_t)(bbase + ts * 64 + rrow) * 96 + sseg;
#pragma unroll
      for (int i = 0; i < 6; i++) st[i] = *(const s16x8*)(gh + i * 8);
      if (tid < 128) {
        int tq = t0 + 2 * (p + 1) + (tid >> 6);
        int tqs = (tq < t1) ? tq : (t1 - 1);
        stq = sq[bbase + tqs * 64 + (tid & 63)];
      }
    }

    // ---- tile A ----
    {
      f32x16 acc = (f32x16){0.f, 0.f, 0.f, 0.f, 0.f, 0.f, 0.f, 0.f,
                            0.f, 0.f, 0.f, 0.f, 0.f, 0.f, 0.f, 0.f};
#pragma unroll
      for (int kc = 0; kc < 6; kc++) {
        s16x8 amh = *(const s16x8*)(mhA + mrow * 104 + kc * 16 + koff);
        acc = __builtin_amdgcn_mfma_f32_32x32x16_bf16(amh, bqh[kc], acc, 0, 0, 0);
        acc = __builtin_amdgcn_mfma_f32_32x32x16_bf16(amh, bql[kc], acc, 0, 0, 0);
      }
      f32x4 sm0 = *(const f32x4*)(sqsA + sqbase);
      f32x4 sm1 = *(const f32x4*)(sqsA + sqbase + 8);
      f32x4 sm2 = *(const f32x4*)(sqsA + sqbase + 16);
      f32x4 sm3 = *(const f32x4*)(sqsA + sqbase + 24);
      int lbase = (ta - t0) * 64;
      float cs[16];
#pragma unroll
      for (int reg = 0; reg < 16; reg++) {
        int g = reg >> 2, e = reg & 3;
        float sqm = (g == 0) ? sm0[e] : (g == 1) ? sm1[e] : (g == 2) ? sm2[e] : sm3[e];
        int mloc = wm * 32 + e + 8 * g + 4 * (lane >> 5);
        float d = fmaf(-2.f, acc[reg], sqr + sqm);
        unsigned u = (__float_as_uint(d) & 0xFFFFFC00u) | (unsigned)(lbase + mloc);
        cs[reg] = __uint_as_float(u);
      }
      sort16(cs);
      bmerge12(fd, cs);
    }
    // ---- tile B (uniform guard: t1 is block-uniform, no barriers inside) ----
    if (tb < t1) {
      f32x16 acc = (f32x16){0.f, 0.f, 0.f, 0.f, 0.f, 0.f, 0.f, 0.f,
                            0.f, 0.f, 0.f, 0.f, 0.f, 0.f, 0.f, 0.f};
#pragma unroll
      for (int kc = 0; kc < 6; kc++) {
        s16x8 amh = *(const s16x8*)(mhB + mrow * 104 + kc * 16 + koff);
        acc = __builtin_amdgcn_mfma_f32_32x32x16_bf16(amh, bqh[kc], acc, 0, 0, 0);
        acc = __builtin_amdgcn_mfma_f32_32x32x16_bf16(amh, bql[kc], acc, 0, 0, 0);
      }
      f32x4 sm0 = *(const f32x4*)(sqsB + sqbase);
      f32x4 sm1 = *(const f32x4*)(sqsB + sqbase + 8);
      f32x4 sm2 = *(const f32x4*)(sqsB + sqbase + 16);
      f32x4 sm3 = *(const f32x4*)(sqsB + sqbase + 24);
      int lbase = (tb - t0) * 64;
      float cs[16];
#pragma unroll
      for (int reg = 0; reg < 16; reg++) {
        int g = reg >> 2, e = reg & 3;
        float sqm = (g == 0) ? sm0[e] : (g == 1) ? sm1[e] : (g == 2) ? sm2[e] : sm3[e];
        int mloc = wm * 32 + e + 8 * g + 4 * (lane >> 5);
        float d = fmaf(-2.f, acc[reg], sqr + sqm);
        unsigned u = (__float_as_uint(d) & 0xFFFFFC00u) | (unsigned)(lbase + mloc);
        cs[reg] = __uint_as_float(u);
      }
      sort16(cs);
      bmerge12(fd, cs);
    }
  }

  // merge 4 sorted partial 12-lists per query via LDS (aliases dead tile A)
  __syncthreads();
  float* cd = smem_f;  // 256 rows x 13 floats = 3328 floats (tile A region)
#pragma unroll
  for (int k = 0; k < 12; k++) cd[(wv * 64 + lane) * 13 + k] = fd[k];
  __syncthreads();
  if (wv == 0) {
    int wva = lane >> 5, ql = lane & 31;
    int ra = wva * 64 + ql, rb = wva * 64 + ql + 32;
    int rc = (wva + 2) * 64 + ql, rd = (wva + 2) * 64 + ql + 32;
    float A[12], B[12];
#pragma unroll
    for (int k = 0; k < 12; k++) { A[k] = cd[ra * 13 + k]; B[k] = cd[rb * 13 + k]; }
    bmerge12(A, B);
    float Cc[12], Dd[12];
#pragma unroll
    for (int k = 0; k < 12; k++) { Cc[k] = cd[rc * 13 + k]; Dd[k] = cd[rd * 13 + k]; }
    bmerge12(Cc, Dd);
    bmerge12(A, Cc);
    size_t base = ((size_t)(bbase + q0 + lane) * MSPLIT + z) * T12;
#pragma unroll
    for (int k = 0; k < T12; k++) {
      int mloc = (int)(__float_as_uint(A[k]) & 0x3FFu) + t0 * 64;
      pk_i[base + k] = bbase + mloc;
    }
  }
}

// ---------------- exact fp32 rescore v4: coop gather + XCD-batch swizzle ------
__global__ __launch_bounds__(256) void rescore_kernel(
    const float* __restrict__ xf, const float* __restrict__ sq,
    const int* __restrict__ pk_i, int* __restrict__ nn) {
  __shared__ float qr[4][96];
  __shared__ float sqq[4];
  int tid = threadIdx.x;
  int qloc = tid >> 6, c = tid & 63;
  int bid = blockIdx.x;
  int qbase = (bid & 7) * NPB + (bid >> 3) * 4;
  for (int f = tid; f < 4 * 96; f += 256)
    qr[f / 96][f % 96] = xf[(size_t)(qbase + f / 96) * 96 + f % 96];
  if (tid < 4) sqq[tid] = sq[qbase + tid];
  __syncthreads();

  int q = qbase + qloc;
  int jv = 0;
  if (c < NCAND) jv = pk_i[(size_t)q * NCAND + c];

  int grp = c >> 3;    // candidate-within-iteration (0..7)
  int chunk = c & 7;   // 12-float chunk of the row (0..7)
  const float4* qp = (const float4*)qr[qloc];
  float4 qv0 = qp[chunk];
  float4 qv1 = qp[chunk + 8];
  float4 qv2 = qp[chunk + 16];

  float dots[6];
#pragma unroll
  for (int it = 0; it < 6; it++) {
    int j = __shfl(jv, it * 8 + grp, 64);
    const float4* mp = (const float4*)(xf + (size_t)j * 96);
    float4 m0 = mp[chunk];
    float4 m1 = mp[chunk + 8];
    float4 m2 = mp[chunk + 16];
    float p = qv0.x * m0.x + qv0.y * m0.y + qv0.z * m0.z + qv0.w * m0.w +
              qv1.x * m1.x + qv1.y * m1.y + qv1.z * m1.z + qv1.w * m1.w +
              qv2.x * m2.x + qv2.y * m2.y + qv2.z * m2.z + qv2.w * m2.w;
    p += __shfl_xor(p, 1, 64);
    p += __shfl_xor(p, 2, 64);
    p += __shfl_xor(p, 4, 64);
    dots[it] = p;
  }

  float g0 = __shfl(dots[0], (c & 7) * 8, 64);
  float g1 = __shfl(dots[1], (c & 7) * 8, 64);
  float g2 = __shfl(dots[2], (c & 7) * 8, 64);
  float g3 = __shfl(dots[3], (c & 7) * 8, 64);
  float g4 = __shfl(dots[4], (c & 7) * 8, 64);
  float g5 = __shfl(dots[5], (c & 7) * 8, 64);
  int itstar = c >> 3;
  float dot = g0;
  dot = (itstar == 1) ? g1 : dot;
  dot = (itstar == 2) ? g2 : dot;
  dot = (itstar == 3) ? g3 : dot;
  dot = (itstar == 4) ? g4 : dot;
  dot = (itstar == 5) ? g5 : dot;

  unsigned long long key = 0xFFFFFFFFFFFFFFFFull;
  if (c < NCAND) {
    float d = (sqq[qloc] - 2.0f * dot) + sq[jv];
    unsigned u = __float_as_uint(d);
    u ^= (u & 0x80000000u) ? 0xFFFFFFFFu : 0x80000000u;
    key = ((unsigned long long)u << 32) | (unsigned)jv;
  }

#pragma unroll
  for (int k = 2; k <= 64; k <<= 1) {
#pragma unroll
    for (int jm = k >> 1; jm >= 1; jm >>= 1) {
      unsigned long long other = __shfl_xor(key, jm, 64);
      bool takeMin = ((c & jm) == 0) == ((c & k) == 0);
      bool sw = (other < key) == takeMin;
      key = sw ? other : key;
    }
  }

  if (c < KNN) {
    nn[(size_t)q * KNN + c] = (int)(unsigned)(key & 0xFFFFFFFFull);
  }
}

// ---------------- fused gather + MFMA EdgeConv GEMM ----------------
// v4: fixed-trip masked gather (R12) + acc1 hoist + XCD-batch swizzle.
__global__ __launch_bounds__(192) void mfma_ec_fused_kernel(
    const unsigned short* __restrict__ A0h, const unsigned short* __restrict__ A0l,
    const float* __restrict__ feat32, const unsigned short* __restrict__ gfh,
    const unsigned short* __restrict__ gfl, int mode,
    const int* __restrict__ nn, const int* __restrict__ kint,
    const unsigned short* __restrict__ Bth, const unsigned short* __restrict__ Btl,
    const float* __restrict__ rs, const float* __restrict__ bias, int relu,
    unsigned short* __restrict__ Oh, unsigned short* __restrict__ Ol) {
  __shared__ float rsL[32];
  __shared__ float bL[96];
  __shared__ __align__(16) unsigned short Sth[32][104];
  __shared__ __align__(16) unsigned short Stl[32][104];
  int tid = threadIdx.x, lane = tid & 63, wv = tid >> 6;
  int bid = blockIdx.x;
  int m0 = (bid & 7) * NPB + (bid >> 3) * 32;  // XCD-batch swizzle
  if (tid < 32) rsL[tid] = rs[m0 + tid];
  if (tid < 96) bL[tid] = bias[tid];

  for (int it = tid; it < 768; it += 192) {
    int nl = it / 24, c4 = it % 24;
    int node = m0 + nl;
    int kc = kint[node];
    const int* nr = nn + (size_t)node * KNN;
    int jj[KNN];
#pragma unroll
    for (int k = 0; k < KNN; k++) jj[k] = nr[k];
    float4 acc = make_float4(0.f, 0.f, 0.f, 0.f);
    if (mode == 0) {
#pragma unroll
      for (int k = 0; k < KNN; k++) {
        float4 v = ((const float4*)(feat32 + (size_t)jj[k] * C))[c4];
        bool on = (k < kc);
        acc.x = on ? acc.x + v.x : acc.x;
        acc.y = on ? acc.y + v.y : acc.y;
        acc.z = on ? acc.z + v.z : acc.z;
        acc.w = on ? acc.w + v.w : acc.w;
      }
    } else {
#pragma unroll
      for (int k = 0; k < KNN; k++) {
        ushort4 h = ((const ushort4*)(gfh + (size_t)jj[k] * C))[c4];
        ushort4 l = ((const ushort4*)(gfl + (size_t)jj[k] * C))[c4];
        bool on = (k < kc);
        acc.x = on ? acc.x + bf2f(h.x) + bf2f(l.x) : acc.x;
        acc.y = on ? acc.y + bf2f(h.y) + bf2f(l.y) : acc.y;
        acc.z = on ? acc.z + bf2f(h.z) + bf2f(l.z) : acc.z;
        acc.w = on ? acc.w + bf2f(h.w) + bf2f(l.w) : acc.w;
      }
    }
    ushort4 h, l;
    h.x = f2bf(acc.x); l.x = f2bf(acc.x - bf2f(h.x));
    h.y = f2bf(acc.y); l.y = f2bf(acc.y - bf2f(h.y));
    h.z = f2bf(acc.z); l.z = f2bf(acc.z - bf2f(h.z));
    h.w = f2bf(acc.w); l.w = f2bf(acc.w - bf2f(h.w));
    *(ushort4*)&Sth[nl][c4 * 4] = h;
    *(ushort4*)&Stl[nl][c4 * 4] = l;
  }

  int koff = (lane >> 5) * 8;
  int arow = m0 + (lane & 31);
  const unsigned short* a0h = A0h + (size_t)arow * 96 + koff;
  const unsigned short* a0l = A0l + (size_t)arow * 96 + koff;
  int rloc = lane & 31;
  int n = wv * 32 + (lane & 31);

  f32x16 acc1 = (f32x16){0.f, 0.f, 0.f, 0.f, 0.f, 0.f, 0.f, 0.f,
                         0.f, 0.f, 0.f, 0.f, 0.f, 0.f, 0.f, 0.f};
  f32x16 acc2 = acc1;

#pragma unroll
  for (int c = 0; c < 6; c++) {
    s16x8 ah = *(const s16x8*)(a0h + c * 16);
    s16x8 al = *(const s16x8*)(a0l + c * 16);
    size_t bo = (size_t)n * 192 + c * 16 + koff;
    s16x8 bh = *(const s16x8*)(Bth + bo);
    s16x8 bl = *(const s16x8*)(Btl + bo);
    acc1 = __builtin_amdgcn_mfma_f32_32x32x16_bf16(ah, bh, acc1, 0, 0, 0);
    acc1 = __builtin_amdgcn_mfma_f32_32x32x16_bf16(al, bh, acc1, 0, 0, 0);
    acc1 = __builtin_amdgcn_mfma_f32_32x32x16_bf16(ah, bl, acc1, 0, 0, 0);
  }
  __syncthreads();

#pragma unroll
  for (int c = 6; c < 12; c++) {
    s16x8 ah = *(const s16x8*)(&Sth[rloc][(c - 6) * 16 + koff]);
    s16x8 al = *(const s16x8*)(&Stl[rloc][(c - 6) * 16 + koff]);
    size_t bo = (size_t)n * 192 + c * 16 + koff;
    s16x8 bh = *(const s16x8*)(Bth + bo);
    s16x8 bl = *(const s16x8*)(Btl + bo);
    acc2 = __builtin_amdgcn_mfma_f32_32x32x16_bf16(ah, bh, acc2, 0, 0, 0);
    acc2 = __builtin_amdgcn_mfma_f32_32x32x16_bf16(al, bh, acc2, 0, 0, 0);
    acc2 = __builtin_amdgcn_mfma_f32_32x32x16_bf16(ah, bl, acc2, 0, 0, 0);
  }

  float bn = bL[n];
#pragma unroll
  for (int reg = 0; reg < 16; reg++) {
    int rl = (reg & 3) + 8 * (reg >> 2) + 4 * (lane >> 5);
    int r = m0 + rl;
    float v = rsL[rl] * (acc1[reg] + bn) + acc2[reg];
    if (relu) v = fmaxf(v, 0.f);
    unsigned short h = f2bf(v);
    Oh[(size_t)r * 96 + n] = h;
    Ol[(size_t)r * 96 + n] = f2bf(v - bf2f(h));
  }
}

// ---------------- MFMA final GEMM + transpose-store: grid (784, 2), block 192 ----
// XCD-batch swizzle on the row dimension (A-reads batch-local).
__global__ __launch_bounds__(192) void mfma_final_kernel(
    const unsigned short* __restrict__ A0h, const unsigned short* __restrict__ A0l,
    const unsigned short* __restrict__ A1h, const unsigned short* __restrict__ A1l,
    const unsigned short* __restrict__ Bth, const unsigned short* __restrict__ Btl,
    const float* __restrict__ bias, float* __restrict__ out) {
  __shared__ float bL[96];
  __shared__ float tt[3][32][33];
  int tid = threadIdx.x, lane = tid & 63, wv = tid >> 6;
  int bid = blockIdx.x;
  int m0 = (bid & 7) * NPB + (bid >> 3) * 32;  // XCD-batch swizzle
  int n0 = blockIdx.y * 96;
  if (tid < 96) bL[tid] = bias[n0 + tid];
  __syncthreads();

  int koff = (lane >> 5) * 8;
  int arow = m0 + (lane & 31);
  const unsigned short* a0h = A0h + (size_t)arow * 96 + koff;
  const unsigned short* a0l = A0l + (size_t)arow * 96 + koff;
  const unsigned short* a1h = A1h + (size_t)arow * 96 + koff;
  const unsigned short* a1l = A1l + (size_t)arow * 96 + koff;
  int nloc = lane & 31;
  int n = n0 + wv * 32 + nloc;

  f32x16 acc = (f32x16){0.f, 0.f, 0.f, 0.f, 0.f, 0.f, 0.f, 0.f,
                        0.f, 0.f, 0.f, 0.f, 0.f, 0.f, 0.f, 0.f};
#pragma unroll
  for (int c = 0; c < 12; c++) {
    s16x8 ah, al;
    if (c < 6) {
      ah = *(const s16x8*)(a0h + c * 16);
      al = *(const s16x8*)(a0l + c * 16);
    } else {
      ah = *(const s16x8*)(a1h + (c - 6) * 16);
      al = *(const s16x8*)(a1l + (c - 6) * 16);
    }
    size_t bo = (size_t)n * 192 + c * 16 + koff;
    s16x8 bh = *(const s16x8*)(Bth + bo);
    s16x8 bl = *(const s16x8*)(Btl + bo);
    acc = __builtin_amdgcn_mfma_f32_32x32x16_bf16(ah, bh, acc, 0, 0, 0);
    acc = __builtin_amdgcn_mfma_f32_32x32x16_bf16(al, bh, acc, 0, 0, 0);
    acc = __builtin_amdgcn_mfma_f32_32x32x16_bf16(ah, bl, acc, 0, 0, 0);
  }

  float bn = bL[wv * 32 + nloc];
#pragma unroll
  for (int reg = 0; reg < 16; reg++) {
    int rl = (reg & 3) + 8 * (reg >> 2) + 4 * (lane >> 5);
    tt[wv][nloc][rl] = fmaxf(acc[reg] + bn, 0.f);
  }
  __builtin_amdgcn_s_waitcnt(0);  // wave-local LDS write->read (R12-proven)
  int gbase = m0 + nloc;  // 32-row tile lies within one batch (3136 % 32 == 0)
  int bb = gbase / NPB, nidx = gbase % NPB;
#pragma unroll
  for (int i = 0; i < 16; i++) {
    int nl = 2 * i + (lane >> 5);
    float v = tt[wv][nl][nloc];
    int ng = n0 + wv * 32 + nl;
    out[(size_t)bb * COUT * NPB + (size_t)ng * NPB + nidx] = v;
  }
}

extern "C" void kernel_launch(void* const* d_in, const int* in_sizes, int n_in,
                              void* d_out, int out_size, void* d_ws, size_t ws_size,
                              hipStream_t stream) {
  const float* x      = (const float*)d_in[0];
  const float* kmap_w = (const float*)d_in[1];
  const float* kmap_b = (const float*)d_in[2];
  const float* kfc_w  = (const float*)d_in[3];
  const float* kfc_b  = (const float*)d_in[4];
  const float* kmu_w  = (const float*)d_in[5];
  const float* kmu_b  = (const float*)d_in[6];
  const float* kdec_w = (const float*)d_in[7];
  const float* kdec_b = (const float*)d_in[8];
  const float* ec1_w  = (const float*)d_in[9];
  const float* ec1_b  = (const float*)d_in[10];
  const float* ec2_w  = (const float*)d_in[11];
  const float* ec2_b  = (const float*)d_in[12];
  const float* fc_w   = (const float*)d_in[13];
  const float* fc_b   = (const float*)d_in[14];
  const float* io_w   = (const float*)d_in[15];
  const float* io_b   = (const float*)d_in[16];
  const float* up_w   = (const float*)d_in[17];
  const float* up_b   = (const float*)d_in[18];

  // ---- workspace layout (liveness-aliased) ----
  char* ws = (char*)d_ws;
  size_t off = 0;
  auto alloc = [&](size_t bytes) -> void* {
    void* p = ws + off;
    off += (bytes + 255) & ~(size_t)255;
    return p;
  };
  const size_t HBF = (size_t)NODES * C * 2;  // bf16 plane (256-aligned)
  float* xf   = (float*)alloc((size_t)NODES * C * 4);
  float* sqb  = (float*)alloc((size_t)NODES * 4);
  float* rs   = (float*)alloc((size_t)NODES * 4);
  int*   kint = (int*)alloc((size_t)NODES * 4);
  int*   nn   = (int*)alloc((size_t)NODES * KNN * 4);
  unsigned short* xh = (unsigned short*)alloc(HBF);
  unsigned short* xl = (unsigned short*)alloc(HBF);
  char* region = (char*)alloc((size_t)NODES * COUT * 4);
  // region timeline: pk_i(4.8M) -> h1 pair -> h2 pair (serial)
  int*   pk_i   = (int*)region;
  unsigned short* h1h = (unsigned short*)region;
  unsigned short* h1l = (unsigned short*)(region + HBF);
  unsigned short* h2h = (unsigned short*)(region + 2 * HBF);
  unsigned short* h2l = (unsigned short*)(region + 3 * HBF);
  float* WkP = (float*)alloc(96 * 64 * 4);
  float* bkP = (float*)alloc(64 * 4);
  float* WdP = (float*)alloc(64 * 9 * 4);
  float* bdP = (float*)alloc(16 * 4);
  float* bPf = (float*)alloc(192 * 4);
  unsigned short* B1h = (unsigned short*)alloc(96 * 192 * 2);
  unsigned short* B1l = (unsigned short*)alloc(96 * 192 * 2);
  unsigned short* B2h = (unsigned short*)alloc(96 * 192 * 2);
  unsigned short* B2l = (unsigned short*)alloc(96 * 192 * 2);
  unsigned short* BFh = (unsigned short*)alloc(192 * 192 * 2);
  unsigned short* BFl = (unsigned short*)alloc(192 * 192 * 2);

  // ---- fused transpose + sq + bf16 split ----
  txsq_kernel<<<dim3(98, 8), 256, 0, stream>>>(x, xf, sqb, xh, xl);

  // ---- one fused fold launch ----
  fold_all_kernel<<<883, 256, 0, stream>>>(
      kmap_w, kmap_b, kfc_w, kfc_b, kmu_w, kmu_b, kdec_w, kdec_b, ec1_w, ec2_w,
      io_w, io_b, fc_w, fc_b, up_w, up_b,
      WkP, bkP, WdP, bdP, bPf, B1h, B1l, B2h, B2l, BFh, BFl);

  // ---- fused VAE head: h64 GEMM + argmax -> kint, rs ----
  gemmhead_kernel<<<392, 256, 0, stream>>>(xf, WkP, bkP, WdP, bdP, kint, rs);

  // ---- kNN filter (v9) + exact rescore (both XCD-batch swizzled) ----
  knn_mfma_kernel<<<1568, 256, 0, stream>>>(xh, xl, sqb, pk_i);
  rescore_kernel<<<6272, 256, 0, stream>>>(xf, sqb, pk_i, nn);

  // ---- EdgeConv layer 1 (relu), gather fused (XCD-batch swizzled) ----
  mfma_ec_fused_kernel<<<784, 192, 0, stream>>>(
      xh, xl, xf, (const unsigned short*)nullptr, (const unsigned short*)nullptr,
      0, nn, kint, B1h, B1l, rs, ec1_b, 1, h1h, h1l);
  // ---- EdgeConv layer 2 (no relu), gather fused ----
  mfma_ec_fused_kernel<<<784, 192, 0, stream>>>(
      h1h, h1l, (const float*)nullptr, h1h, h1l,
      1, nn, kint, B2h, B2l, rs, ec2_b, 0, h2h, h2l);
  // ---- final folded GEMM + transpose-store (XCD-batch swizzled) ----
  mfma_final_kernel<<<dim3(784, 2), 192, 0, stream>>>(xh, xl, h2h, h2l, BFh, BFl,
                                                      bPf, (float*)d_out);
}